// Round 14
// baseline (140.638 us; speedup 1.0000x reference)
//
#include <hip/hip_runtime.h>
#include <hip/hip_bf16.h>
#include <cfloat>
#include <climits>
#include <cmath>

// Problem constants: B=32, S=2048, H=1024, K=4, PREV=2, R=8
#define BB 32
#define SS 2048
#define HH 1024
#define KK 4
#define CH 32  // s-chunks per batch row in fused_attn (64 rows each)

// ---------------------------------------------------------------------------
// K1: gates partials, b-split=2. grid (24, 16, 2) = (j-tile, kc, bq).
// part[(kc*32 + bq*16+bi)*6144 + j] = sum_{k in chunk64} A[b,k]*W[j,k]
// 768 blocks (~3/CU); W read 2x (48 MB) vs R12's 4x (96 MB); acc[16].
// ---------------------------------------------------------------------------
__global__ __launch_bounds__(256) void gates_partial(
    const float* __restrict__ x, const float* __restrict__ h_old,
    const float* __restrict__ W_ih, const float* __restrict__ W_hh,
    float* __restrict__ part) {
  int t = threadIdx.x;
  int jb = blockIdx.x;       // 0..23
  int kc = blockIdx.y;       // 0..15
  int bq = blockIdx.z;       // 0..1
  int k0 = kc * 64;
  bool second = (jb >= 12);
  const float* A = (second ? h_old : x) + (size_t)(bq * 16) * HH;
  const float* W = second ? W_hh : W_ih;
  int j0 = jb * 256;
  int jr = j0 - (second ? 3072 : 0);
  const float* wp = W + (size_t)(jr + t) * HH + k0;
  float acc[16];
#pragma unroll
  for (int bi = 0; bi < 16; bi++) acc[bi] = 0.f;
#pragma unroll
  for (int kk = 0; kk < 64; kk += 4) {
    float4 wv = *(const float4*)(wp + kk);
#pragma unroll
    for (int bi = 0; bi < 16; bi++) {
      float4 a = *(const float4*)(A + (size_t)bi * HH + k0 + kk);  // uniform
      acc[bi] += a.x * wv.x + a.y * wv.y + a.z * wv.z + a.w * wv.w;
    }
  }
  float* pb = part + ((size_t)kc * 32 + bq * 16) * 6144 + j0 + t;
#pragma unroll
  for (int bi = 0; bi < 16; bi++) pb[(size_t)bi * 6144] = acc[bi];
}

// ---------------------------------------------------------------------------
// K2: gate-reduce (16 chunks; 96 independent loads/thread) + GRU pointwise.
// grid (32, 4) = (b, h-tile), block 256. [R12 verbatim]
// ---------------------------------------------------------------------------
__global__ __launch_bounds__(256) void gru_pw(
    const float* __restrict__ part, const float* __restrict__ b_ih,
    const float* __restrict__ b_hh, const float* __restrict__ h_old,
    float* __restrict__ h_new) {
  int t = threadIdx.x;
  int b = blockIdx.x;
  int h = blockIdx.y * 256 + t;
  float s0 = 0.f, s1 = 0.f, s2 = 0.f, s3 = 0.f, s4 = 0.f, s5 = 0.f;
#pragma unroll
  for (int c = 0; c < 16; c++) {
    const float* p = part + ((size_t)c * 32 + b) * 6144;
    s0 += p[h];
    s1 += p[1024 + h];
    s2 += p[2048 + h];
    s3 += p[3072 + h];
    s4 += p[4096 + h];
    s5 += p[5120 + h];
  }
  float ir = s0 + b_ih[h], iz = s1 + b_ih[1024 + h], in_ = s2 + b_ih[2048 + h];
  float hr = s3 + b_hh[h], hz = s4 + b_hh[1024 + h], hn = s5 + b_hh[2048 + h];
  float r = 1.f / (1.f + expf(-(ir + hr)));
  float z = 1.f / (1.f + expf(-(iz + hz)));
  float n = tanhf(in_ + r * hn);
  h_new[b * HH + h] = (1.f - z) * n + z * h_old[b * HH + h];
}

// ---------------------------------------------------------------------------
// K3: q partials, b-split. grid (4, 32, 4) = (n-tile, j-chunk, bq). [R12]
// ---------------------------------------------------------------------------
__global__ __launch_bounds__(256) void q_partial(const float* __restrict__ hnew,
                                                 const float* __restrict__ Wk,
                                                 float* __restrict__ qpart) {
  int t = threadIdx.x;
  int n = blockIdx.x * 256 + t;
  int j0 = blockIdx.y * 32;
  int b0 = blockIdx.z * 8;
  float acc[8];
#pragma unroll
  for (int bi = 0; bi < 8; bi++) acc[bi] = 0.f;
#pragma unroll
  for (int j = 0; j < 32; j += 4) {
    float w0 = Wk[(size_t)(j0 + j + 0) * HH + n];
    float w1 = Wk[(size_t)(j0 + j + 1) * HH + n];
    float w2 = Wk[(size_t)(j0 + j + 2) * HH + n];
    float w3 = Wk[(size_t)(j0 + j + 3) * HH + n];
#pragma unroll
    for (int bi = 0; bi < 8; bi++) {
      float4 hv = *(const float4*)(hnew + (size_t)(b0 + bi) * HH + j0 + j);  // uniform
      acc[bi] += hv.x * w0 + hv.y * w1 + hv.z * w2 + hv.w * w3;
    }
  }
  float* pb = qpart + ((size_t)blockIdx.y * 32 + b0) * 1024 + n;
#pragma unroll
  for (int bi = 0; bi < 8; bi++) pb[(size_t)bi * 1024] = acc[bi];
}

// ---------------------------------------------------------------------------
// K4: q = sum of 32 j-chunk partials. grid 128. [R12 verbatim]
// ---------------------------------------------------------------------------
__global__ __launch_bounds__(256) void q_reduce(const float* __restrict__ qpart,
                                                float* __restrict__ q) {
  int t = threadIdx.x;
  int b = blockIdx.x >> 2;
  int n = (blockIdx.x & 3) * 256 + t;
  float s = 0.f;
#pragma unroll
  for (int jc = 0; jc < 32; jc++) s += qpart[((size_t)jc * 32 + b) * 1024 + n];
  q[b * HH + n] = s;
}

// ---------------------------------------------------------------------------
// K5: fused attention (single HBM pass over eo). [R12 verbatim]
// ---------------------------------------------------------------------------
__global__ __launch_bounds__(256) void fused_attn(
    const float* __restrict__ eo, const float* __restrict__ q,
    const float* __restrict__ h_new, const float* __restrict__ bk,
    const float* __restrict__ mask, float* __restrict__ logits,
    float* __restrict__ c0part, float* __restrict__ msum_part) {
  __shared__ float q_lds[HH];
  __shared__ float wred[4];
  __shared__ float cacc[4][1024];
  __shared__ float cms[4][2];
  int b = blockIdx.y, sc = blockIdx.x, t = threadIdx.x;
  int w = t >> 6, lane = t & 63;
  {
    float4 qs = *(const float4*)(q + (size_t)b * HH + 4 * t);
    *(float4*)&q_lds[4 * t] = qs;
    float4 hv = *(const float4*)(h_new + (size_t)b * HH + 4 * t);
    float4 kv = *(const float4*)(bk + 4 * t);
    float p = hv.x * kv.x + hv.y * kv.y + hv.z * kv.z + hv.w * kv.w;
#pragma unroll
    for (int off = 32; off; off >>= 1) p += __shfl_xor(p, off);
    if (lane == 0) wred[w] = p;
  }
  __syncthreads();
  float hb = wred[0] + wred[1] + wred[2] + wred[3];
  float4 qv[4];
#pragma unroll
  for (int i = 0; i < 4; i++) qv[i] = *(const float4*)&q_lds[(i * 64 + lane) * 4];

  float m = -FLT_MAX, sum = 0.f;
  float4 acc[4];
#pragma unroll
  for (int i = 0; i < 4; i++) acc[i] = make_float4(0.f, 0.f, 0.f, 0.f);
  int rbase = sc * 64 + w * 16;
  for (int tile = 0; tile < 8; tile++) {
    int r0 = rbase + tile * 2;
    float4 rv[2][4];
#pragma unroll
    for (int rr = 0; rr < 2; rr++) {
      const float4* e4 = (const float4*)(eo + ((size_t)b * SS + r0 + rr) * HH);
#pragma unroll
      for (int i = 0; i < 4; i++) rv[rr][i] = e4[i * 64 + lane];
    }
    float p0 = 0.f, p1 = 0.f;
#pragma unroll
    for (int i = 0; i < 4; i++) {
      p0 += rv[0][i].x * qv[i].x + rv[0][i].y * qv[i].y +
            rv[0][i].z * qv[i].z + rv[0][i].w * qv[i].w;
      p1 += rv[1][i].x * qv[i].x + rv[1][i].y * qv[i].y +
            rv[1][i].z * qv[i].z + rv[1][i].w * qv[i].w;
    }
#pragma unroll
    for (int off = 32; off; off >>= 1) {
      p0 += __shfl_xor(p0, off);
      p1 += __shfl_xor(p1, off);
    }
    float lv0 = (p0 + hb) * 0.03125f + mask[(size_t)b * SS + r0];
    float lv1 = (p1 + hb) * 0.03125f + mask[(size_t)b * SS + r0 + 1];
    if (lane == 0) {
      logits[(size_t)b * SS + r0] = lv0;
      logits[(size_t)b * SS + r0 + 1] = lv1;
    }
    float m_new = fmaxf(m, fmaxf(lv0, lv1));
    float scale = expf(m - m_new);  // exp(-inf)=0 on first tile
    float w0 = expf(lv0 - m_new), w1 = expf(lv1 - m_new);
    sum = sum * scale + w0 + w1;
#pragma unroll
    for (int i = 0; i < 4; i++) {
      acc[i].x = acc[i].x * scale + w0 * rv[0][i].x + w1 * rv[1][i].x;
      acc[i].y = acc[i].y * scale + w0 * rv[0][i].y + w1 * rv[1][i].y;
      acc[i].z = acc[i].z * scale + w0 * rv[0][i].z + w1 * rv[1][i].z;
      acc[i].w = acc[i].w * scale + w0 * rv[0][i].w + w1 * rv[1][i].w;
    }
    m = m_new;
  }
#pragma unroll
  for (int i = 0; i < 4; i++) *(float4*)&cacc[w][i * 256 + lane * 4] = acc[i];
  if (lane == 0) { cms[w][0] = m; cms[w][1] = sum; }
  __syncthreads();
  float m0 = cms[0][0], m1 = cms[1][0], m2 = cms[2][0], m3 = cms[3][0];
  float mb = fmaxf(fmaxf(m0, m1), fmaxf(m2, m3));
  float wt0 = expf(m0 - mb), wt1 = expf(m1 - mb), wt2 = expf(m2 - mb),
        wt3 = expf(m3 - mb);
  float sb = cms[0][1] * wt0 + cms[1][1] * wt1 + cms[2][1] * wt2 + cms[3][1] * wt3;
  float4 a0 = *(float4*)&cacc[0][4 * t];
  float4 a1 = *(float4*)&cacc[1][4 * t];
  float4 a2 = *(float4*)&cacc[2][4 * t];
  float4 a3 = *(float4*)&cacc[3][4 * t];
  float4 r;
  r.x = wt0 * a0.x + wt1 * a1.x + wt2 * a2.x + wt3 * a3.x;
  r.y = wt0 * a0.y + wt1 * a1.y + wt2 * a2.y + wt3 * a3.y;
  r.z = wt0 * a0.z + wt1 * a1.z + wt2 * a2.z + wt3 * a3.z;
  r.w = wt0 * a0.w + wt1 * a1.w + wt2 * a2.w + wt3 * a3.w;
  *(float4*)(c0part + ((size_t)sc * 32 + b) * 1024 + 4 * t) = r;
  if (t == 0) {
    msum_part[((size_t)sc * 32 + b) * 2 + 0] = mb;
    msum_part[((size_t)sc * 32 + b) * 2 + 1] = sb;
  }
}

// ---------------------------------------------------------------------------
// K6: grid 160. Blocks 0..127: c0 combine. Blocks 128..159: top-4. [R12]
// ---------------------------------------------------------------------------
__device__ __forceinline__ bool vi_better(float av, int ai, float bv, int bi) {
  return av > bv || (av == bv && ai < bi);
}

__global__ __launch_bounds__(256) void attn_finish(
    const float* __restrict__ c0part, const float* __restrict__ msum_part,
    const float* __restrict__ logits, float* __restrict__ c0,
    float* __restrict__ scores, int* __restrict__ sent) {
  int bid = blockIdx.x, t = threadIdx.x;
  int b = (bid < 128) ? (bid >> 2) : (bid - 128);
  float m = -FLT_MAX;
  float ms[CH];
#pragma unroll
  for (int c = 0; c < CH; c++) {
    ms[c] = msum_part[((size_t)c * 32 + b) * 2 + 0];
    m = fmaxf(m, ms[c]);
  }
  float sum = 0.f;
  float wc[CH];
#pragma unroll
  for (int c = 0; c < CH; c++) {
    wc[c] = expf(ms[c] - m);
    sum += msum_part[((size_t)c * 32 + b) * 2 + 1] * wc[c];
  }
  float inv = 1.f / sum;

  if (bid < 128) {
    int h = (bid & 3) * 256 + t;
    float a = 0.f;
#pragma unroll
    for (int c = 0; c < CH; c++)
      a += wc[c] * c0part[((size_t)c * 32 + b) * 1024 + h];
    c0[(size_t)b * HH + h] = a * inv;
    return;
  }

  float tv0 = -FLT_MAX, tv1 = -FLT_MAX, tv2 = -FLT_MAX, tv3 = -FLT_MAX;
  int ti0 = INT_MAX, ti1 = INT_MAX, ti2 = INT_MAX, ti3 = INT_MAX;
#pragma unroll
  for (int it = 0; it < 8; it++) {
    int idx = it * 256 + t;
    float v = logits[(size_t)b * SS + idx];
    if (vi_better(v, idx, tv3, ti3)) {
      tv3 = v; ti3 = idx;
      if (vi_better(tv3, ti3, tv2, ti2)) { float fv = tv2; int fi = ti2; tv2 = tv3; ti2 = ti3; tv3 = fv; ti3 = fi; }
      if (vi_better(tv2, ti2, tv1, ti1)) { float fv = tv1; int fi = ti1; tv1 = tv2; ti1 = ti2; tv2 = fv; ti2 = fi; }
      if (vi_better(tv1, ti1, tv0, ti0)) { float fv = tv0; int fi = ti0; tv0 = tv1; ti0 = ti1; tv1 = fv; ti1 = fi; }
    }
  }
  __shared__ float sv[256][4];
  __shared__ int si[256][4];
  sv[t][0] = tv0; sv[t][1] = tv1; sv[t][2] = tv2; sv[t][3] = tv3;
  si[t][0] = ti0; si[t][1] = ti1; si[t][2] = ti2; si[t][3] = ti3;
  __syncthreads();
  for (int off = 128; off; off >>= 1) {
    if (t < off) {
      float bv0 = sv[t + off][0], bv1 = sv[t + off][1], bv2 = sv[t + off][2], bv3 = sv[t + off][3];
      int bi0 = si[t + off][0], bi1 = si[t + off][1], bi2 = si[t + off][2], bi3 = si[t + off][3];
      float mv0, mv1, mv2, mv3; int mi0, mi1, mi2, mi3;
      if (vi_better(tv0, ti0, bv3, bi3)) { mv0 = tv0; mi0 = ti0; } else { mv0 = bv3; mi0 = bi3; }
      if (vi_better(tv1, ti1, bv2, bi2)) { mv1 = tv1; mi1 = ti1; } else { mv1 = bv2; mi1 = bi2; }
      if (vi_better(tv2, ti2, bv1, bi1)) { mv2 = tv2; mi2 = ti2; } else { mv2 = bv1; mi2 = bi1; }
      if (vi_better(tv3, ti3, bv0, bi0)) { mv3 = tv3; mi3 = ti3; } else { mv3 = bv0; mi3 = bi0; }
      if (!vi_better(mv0, mi0, mv2, mi2)) { float fv = mv0; int fi = mi0; mv0 = mv2; mi0 = mi2; mv2 = fv; mi2 = fi; }
      if (!vi_better(mv1, mi1, mv3, mi3)) { float fv = mv1; int fi = mi1; mv1 = mv3; mi1 = mi3; mv3 = fv; mi3 = fi; }
      if (!vi_better(mv0, mi0, mv1, mi1)) { float fv = mv0; int fi = mi0; mv0 = mv1; mi0 = mi1; mv1 = fv; mi1 = fi; }
      if (!vi_better(mv2, mi2, mv3, mi3)) { float fv = mv2; int fi = mi2; mv2 = mv3; mi2 = mi3; mv3 = fv; mi3 = fi; }
      tv0 = mv0; tv1 = mv1; tv2 = mv2; tv3 = mv3;
      ti0 = mi0; ti1 = mi1; ti2 = mi2; ti3 = mi3;
      sv[t][0] = tv0; sv[t][1] = tv1; sv[t][2] = tv2; sv[t][3] = tv3;
      si[t][0] = ti0; si[t][1] = ti1; si[t][2] = ti2; si[t][3] = ti3;
    }
    __syncthreads();
  }
  if (t == 0) {
    scores[b * KK + 0] = expf(tv0 - m) * inv; sent[b * KK + 0] = ti0;
    scores[b * KK + 1] = expf(tv1 - m) * inv; sent[b * KK + 1] = ti1;
    scores[b * KK + 2] = expf(tv2 - m) * inv; sent[b * KK + 2] = ti2;
    scores[b * KK + 3] = expf(tv3 - m) * inv; sent[b * KK + 3] = ti3;
  }
}

// ---------------------------------------------------------------------------
// K7: selection + ctx (shuffle-free) + gathers. grid (4,32). [R12 verbatim]
// ---------------------------------------------------------------------------
__global__ __launch_bounds__(256) void ctx_sel_gather(
    const float* __restrict__ scores, const int* __restrict__ sent,
    const float* __restrict__ evidence, const int* __restrict__ esi,
    const float* __restrict__ Wv, const float* __restrict__ bvec,
    const float* __restrict__ c0, const float* __restrict__ hnew,
    const float* __restrict__ attn_in, const float* __restrict__ logits,
    const float* __restrict__ mask, float* __restrict__ out0,
    float* __restrict__ out1, float* __restrict__ out2,
    float* __restrict__ out3, float* __restrict__ out4,
    float* __restrict__ out5) {
  __shared__ int s_sh;
  __shared__ float cs[HH];
  int jq = blockIdx.x, b = blockIdx.y, t = threadIdx.x;
  if (t == 0) {
    int r = b >> 2, j = b & 3;
    float ls[16];
    bool used[16];
    for (int k1 = 0; k1 < 4; k1++)
      for (int k2 = 0; k2 < 4; k2++)
        ls[k1 * 4 + k2] = -logf(scores[(r * 4 + k1) * 4 + k2]) + evidence[r * 4 + k1];
    for (int i = 0; i < 16; i++) used[i] = false;
    int best = 0;
    float bvv = FLT_MAX;
    for (int jj = 0; jj <= j; jj++) {
      best = 0;
      bvv = FLT_MAX;
      for (int i = 0; i < 16; i++)
        if (!used[i] && ls[i] < bvv) { bvv = ls[i]; best = i; }
      used[best] = true;
    }
    int k1 = best >> 2, k2 = best & 3;
    int sSel = r * 4 + k1;
    s_sh = sSel;
    if (jq == 0) {
      out5[b] = bvv;
      out2[b * 3 + 0] = (float)esi[sSel * 2 + 0];
      out2[b * 3 + 1] = (float)esi[sSel * 2 + 1];
      out2[b * 3 + 2] = (float)sent[sSel * 4 + k2];
    }
  }
  __syncthreads();
  int s = s_sh;
  *(float4*)&cs[4 * t] = *(const float4*)(c0 + (size_t)s * HH + 4 * t);
  __syncthreads();
  {
    int j = jq * 256 + t;
    const float4* w4 = (const float4*)(Wv + (size_t)j * HH);
    float acc = bvec[j];
#pragma unroll 8
    for (int k4 = 0; k4 < 256; k4++) {
      float4 wv = w4[k4];
      float4 cc = *(const float4*)&cs[4 * k4];
      acc += wv.x * cc.x + wv.y * cc.y + wv.z * cc.z + wv.w * cc.w;
    }
    out0[(size_t)b * HH + j] = acc;
  }
  out1[(size_t)b * HH + jq * 256 + t] = hnew[(size_t)s * HH + jq * 256 + t];
#pragma unroll
  for (int p = 0; p < 2; p++) {
    *(float2*)(out3 + ((size_t)p * BB + b) * SS + jq * 512 + 2 * t) =
        *(const float2*)(attn_in + ((size_t)p * BB + s) * SS + jq * 512 + 2 * t);
  }
  *(float2*)(out3 + ((size_t)2 * BB + b) * SS + jq * 512 + 2 * t) =
      *(const float2*)(logits + (size_t)s * SS + jq * 512 + 2 * t);
  *(float2*)(out4 + (size_t)b * SS + jq * 512 + 2 * t) =
      *(const float2*)(mask + (size_t)s * SS + jq * 512 + 2 * t);
}

extern "C" void kernel_launch(void* const* d_in, const int* in_sizes, int n_in,
                              void* d_out, int out_size, void* d_ws, size_t ws_size,
                              hipStream_t stream) {
  const float* h_old = (const float*)d_in[0];
  const float* x     = (const float*)d_in[1];
  const float* eo    = (const float*)d_in[2];
  const float* attn_in = (const float*)d_in[3];
  const float* mask  = (const float*)d_in[4];
  const float* evidence = (const float*)d_in[5];
  const int*   esi   = (const int*)d_in[6];
  const float* W_ih  = (const float*)d_in[7];
  const float* W_hh  = (const float*)d_in[8];
  const float* b_ih  = (const float*)d_in[9];
  const float* b_hh  = (const float*)d_in[10];
  const float* Wk    = (const float*)d_in[11];
  const float* bk    = (const float*)d_in[12];
  const float* Wv    = (const float*)d_in[13];
  const float* bv    = (const float*)d_in[14];

  float* w = (float*)d_ws;
  float* h_new  = w + 0;          // 32768
  float* q      = w + 32768;      // 32768
  float* logits = w + 65536;      // 65536
  float* scores = w + 131072;     // 128
  int*   sent   = (int*)(w + 131200);  // 128
  float* c0     = w + 131328;     // 32768
  float* msum_part = w + 164096;  // 2048
  float* c0part = w + 166144;     // 1,048,576
  float* gpart  = w + 1214720;    // 3,145,728
  float* qpart  = w + 4360448;    // 1,048,576

  float* out0 = (float*)d_out;   // result (32,1,1024)
  float* out1 = out0 + 32768;    // hidden (1,32,1024)
  float* out2 = out1 + 32768;    // new_evidence_sentence_index (32,3)
  float* out3 = out2 + 96;       // new_attention_scores (3,32,1,2048)
  float* out4 = out3 + 196608;   // new_attention_mask (32,1,2048)
  float* out5 = out4 + 65536;    // new_evidence_scores (32,)

  gates_partial<<<dim3(24, 16, 2), 256, 0, stream>>>(x, h_old, W_ih, W_hh, gpart);
  gru_pw<<<dim3(32, 4), 256, 0, stream>>>(gpart, b_ih, b_hh, h_old, h_new);
  q_partial<<<dim3(4, 32, 4), 256, 0, stream>>>(h_new, Wk, qpart);
  q_reduce<<<128, 256, 0, stream>>>(qpart, q);
  fused_attn<<<dim3(CH, BB), 256, 0, stream>>>(eo, q, h_new, bk, mask, logits,
                                               c0part, msum_part);
  attn_finish<<<160, 256, 0, stream>>>(c0part, msum_part, logits, c0, scores, sent);
  ctx_sel_gather<<<dim3(4, BB), 256, 0, stream>>>(
      scores, sent, evidence, esi, Wv, bv, c0, h_new, attn_in, logits, mask,
      out0, out1, out2, out3, out4, out5);
}

// Round 15
// 126.921 us; speedup vs baseline: 1.1081x; 1.1081x over previous
//
#include <hip/hip_runtime.h>
#include <hip/hip_bf16.h>
#include <cfloat>
#include <climits>
#include <cmath>

// Problem constants: B=32, S=2048, H=1024, K=4, PREV=2, R=8
#define BB 32
#define SS 2048
#define HH 1024
#define KK 4
#define CH 32  // s-chunks per batch row in fused_attn (64 rows each)

// ---------------------------------------------------------------------------
// K1: gates partials, b-split for TLP. grid (24, 16, 4) = (j-tile, kc, bq).
// part[(kc*32 + bq*8+bi)*6144 + j] = sum_{k in chunk64} A[b,k]*W[j,k]
// 1536 blocks (~6/CU); 512 FMA/thread; 8-deep uniform-load ILP.
// ---------------------------------------------------------------------------
__global__ __launch_bounds__(256) void gates_partial(
    const float* __restrict__ x, const float* __restrict__ h_old,
    const float* __restrict__ W_ih, const float* __restrict__ W_hh,
    float* __restrict__ part) {
  int t = threadIdx.x;
  int jb = blockIdx.x;       // 0..23
  int kc = blockIdx.y;       // 0..15
  int bq = blockIdx.z;       // 0..3
  int k0 = kc * 64;
  bool second = (jb >= 12);
  const float* A = (second ? h_old : x) + (size_t)(bq * 8) * HH;
  const float* W = second ? W_hh : W_ih;
  int j0 = jb * 256;
  int jr = j0 - (second ? 3072 : 0);
  const float* wp = W + (size_t)(jr + t) * HH + k0;
  float acc[8];
#pragma unroll
  for (int bi = 0; bi < 8; bi++) acc[bi] = 0.f;
#pragma unroll
  for (int kk = 0; kk < 64; kk += 4) {
    float4 wv = *(const float4*)(wp + kk);
#pragma unroll
    for (int bi = 0; bi < 8; bi++) {
      float4 a = *(const float4*)(A + (size_t)bi * HH + k0 + kk);  // uniform
      acc[bi] += a.x * wv.x + a.y * wv.y + a.z * wv.z + a.w * wv.w;
    }
  }
  float* pb = part + ((size_t)kc * 32 + bq * 8) * 6144 + j0 + t;
#pragma unroll
  for (int bi = 0; bi < 8; bi++) pb[(size_t)bi * 6144] = acc[bi];
}

// ---------------------------------------------------------------------------
// K2: gate-reduce (16 chunks; 96 independent loads/thread) + GRU pointwise.
// grid (32, 4) = (b, h-tile), block 256.
// ---------------------------------------------------------------------------
__global__ __launch_bounds__(256) void gru_pw(
    const float* __restrict__ part, const float* __restrict__ b_ih,
    const float* __restrict__ b_hh, const float* __restrict__ h_old,
    float* __restrict__ h_new) {
  int t = threadIdx.x;
  int b = blockIdx.x;
  int h = blockIdx.y * 256 + t;
  float s0 = 0.f, s1 = 0.f, s2 = 0.f, s3 = 0.f, s4 = 0.f, s5 = 0.f;
#pragma unroll
  for (int c = 0; c < 16; c++) {
    const float* p = part + ((size_t)c * 32 + b) * 6144;
    s0 += p[h];
    s1 += p[1024 + h];
    s2 += p[2048 + h];
    s3 += p[3072 + h];
    s4 += p[4096 + h];
    s5 += p[5120 + h];
  }
  float ir = s0 + b_ih[h], iz = s1 + b_ih[1024 + h], in_ = s2 + b_ih[2048 + h];
  float hr = s3 + b_hh[h], hz = s4 + b_hh[1024 + h], hn = s5 + b_hh[2048 + h];
  float r = 1.f / (1.f + expf(-(ir + hr)));
  float z = 1.f / (1.f + expf(-(iz + hz)));
  float n = tanhf(in_ + r * hn);
  h_new[b * HH + h] = (1.f - z) * n + z * h_old[b * HH + h];
}

// ---------------------------------------------------------------------------
// K3: q partials, b-split. grid (4, 32, 4) = (n-tile, j-chunk, bq), block 256.
// qpart[(jc*32 + b)*1024 + n] = sum_{j in chunk32} h_new[b,j] * Wk[j,n]
// 512 blocks; 256 FMA/thread; coalesced Wk loads (lane-per-n).
// ---------------------------------------------------------------------------
__global__ __launch_bounds__(256) void q_partial(const float* __restrict__ hnew,
                                                 const float* __restrict__ Wk,
                                                 float* __restrict__ qpart) {
  int t = threadIdx.x;
  int n = blockIdx.x * 256 + t;
  int j0 = blockIdx.y * 32;
  int b0 = blockIdx.z * 8;
  float acc[8];
#pragma unroll
  for (int bi = 0; bi < 8; bi++) acc[bi] = 0.f;
#pragma unroll
  for (int j = 0; j < 32; j += 4) {
    float w0 = Wk[(size_t)(j0 + j + 0) * HH + n];
    float w1 = Wk[(size_t)(j0 + j + 1) * HH + n];
    float w2 = Wk[(size_t)(j0 + j + 2) * HH + n];
    float w3 = Wk[(size_t)(j0 + j + 3) * HH + n];
#pragma unroll
    for (int bi = 0; bi < 8; bi++) {
      float4 hv = *(const float4*)(hnew + (size_t)(b0 + bi) * HH + j0 + j);  // uniform
      acc[bi] += hv.x * w0 + hv.y * w1 + hv.z * w2 + hv.w * w3;
    }
  }
  float* pb = qpart + ((size_t)blockIdx.y * 32 + b0) * 1024 + n;
#pragma unroll
  for (int bi = 0; bi < 8; bi++) pb[(size_t)bi * 1024] = acc[bi];
}

// ---------------------------------------------------------------------------
// K4: q = sum of 32 j-chunk partials (32 independent strided loads).
// grid 128 (b = bid>>2, n-tile = bid&3), block 256.
// ---------------------------------------------------------------------------
__global__ __launch_bounds__(256) void q_reduce(const float* __restrict__ qpart,
                                                float* __restrict__ q) {
  int t = threadIdx.x;
  int b = blockIdx.x >> 2;
  int n = (blockIdx.x & 3) * 256 + t;
  float s = 0.f;
#pragma unroll
  for (int jc = 0; jc < 32; jc++) s += qpart[((size_t)jc * 32 + b) * 1024 + n];
  q[b * HH + n] = s;
}

// ---------------------------------------------------------------------------
// K5: fused attention (single HBM pass over eo). R10 body; preamble reads the
// fully-reduced q directly, hbk block-dot in preamble.
// ---------------------------------------------------------------------------
__global__ __launch_bounds__(256) void fused_attn(
    const float* __restrict__ eo, const float* __restrict__ q,
    const float* __restrict__ h_new, const float* __restrict__ bk,
    const float* __restrict__ mask, float* __restrict__ logits,
    float* __restrict__ c0part, float* __restrict__ msum_part) {
  __shared__ float q_lds[HH];
  __shared__ float wred[4];
  __shared__ float cacc[4][1024];
  __shared__ float cms[4][2];
  int b = blockIdx.y, sc = blockIdx.x, t = threadIdx.x;
  int w = t >> 6, lane = t & 63;
  // ---- preamble: q stage + hbk block dot ----
  {
    float4 qs = *(const float4*)(q + (size_t)b * HH + 4 * t);
    *(float4*)&q_lds[4 * t] = qs;
    float4 hv = *(const float4*)(h_new + (size_t)b * HH + 4 * t);
    float4 kv = *(const float4*)(bk + 4 * t);
    float p = hv.x * kv.x + hv.y * kv.y + hv.z * kv.z + hv.w * kv.w;
#pragma unroll
    for (int off = 32; off; off >>= 1) p += __shfl_xor(p, off);
    if (lane == 0) wred[w] = p;
  }
  __syncthreads();
  float hb = wred[0] + wred[1] + wred[2] + wred[3];
  float4 qv[4];
#pragma unroll
  for (int i = 0; i < 4; i++) qv[i] = *(const float4*)&q_lds[(i * 64 + lane) * 4];

  float m = -FLT_MAX, sum = 0.f;
  float4 acc[4];
#pragma unroll
  for (int i = 0; i < 4; i++) acc[i] = make_float4(0.f, 0.f, 0.f, 0.f);
  int rbase = sc * 64 + w * 16;
  // ---- main loop ----
  for (int tile = 0; tile < 8; tile++) {
    int r0 = rbase + tile * 2;
    float4 rv[2][4];
#pragma unroll
    for (int rr = 0; rr < 2; rr++) {
      const float4* e4 = (const float4*)(eo + ((size_t)b * SS + r0 + rr) * HH);
#pragma unroll
      for (int i = 0; i < 4; i++) rv[rr][i] = e4[i * 64 + lane];
    }
    float p0 = 0.f, p1 = 0.f;
#pragma unroll
    for (int i = 0; i < 4; i++) {
      p0 += rv[0][i].x * qv[i].x + rv[0][i].y * qv[i].y +
            rv[0][i].z * qv[i].z + rv[0][i].w * qv[i].w;
      p1 += rv[1][i].x * qv[i].x + rv[1][i].y * qv[i].y +
            rv[1][i].z * qv[i].z + rv[1][i].w * qv[i].w;
    }
#pragma unroll
    for (int off = 32; off; off >>= 1) {
      p0 += __shfl_xor(p0, off);
      p1 += __shfl_xor(p1, off);
    }
    float lv0 = (p0 + hb) * 0.03125f + mask[(size_t)b * SS + r0];
    float lv1 = (p1 + hb) * 0.03125f + mask[(size_t)b * SS + r0 + 1];
    if (lane == 0) {
      logits[(size_t)b * SS + r0] = lv0;
      logits[(size_t)b * SS + r0 + 1] = lv1;
    }
    float m_new = fmaxf(m, fmaxf(lv0, lv1));
    float scale = expf(m - m_new);  // exp(-inf)=0 on first tile
    float w0 = expf(lv0 - m_new), w1 = expf(lv1 - m_new);
    sum = sum * scale + w0 + w1;
#pragma unroll
    for (int i = 0; i < 4; i++) {
      acc[i].x = acc[i].x * scale + w0 * rv[0][i].x + w1 * rv[1][i].x;
      acc[i].y = acc[i].y * scale + w0 * rv[0][i].y + w1 * rv[1][i].y;
      acc[i].z = acc[i].z * scale + w0 * rv[0][i].z + w1 * rv[1][i].z;
      acc[i].w = acc[i].w * scale + w0 * rv[0][i].w + w1 * rv[1][i].w;
    }
    m = m_new;
  }
  // ---- block combine ----
#pragma unroll
  for (int i = 0; i < 4; i++) *(float4*)&cacc[w][i * 256 + lane * 4] = acc[i];
  if (lane == 0) { cms[w][0] = m; cms[w][1] = sum; }
  __syncthreads();
  float m0 = cms[0][0], m1 = cms[1][0], m2 = cms[2][0], m3 = cms[3][0];
  float mb = fmaxf(fmaxf(m0, m1), fmaxf(m2, m3));
  float wt0 = expf(m0 - mb), wt1 = expf(m1 - mb), wt2 = expf(m2 - mb),
        wt3 = expf(m3 - mb);
  float sb = cms[0][1] * wt0 + cms[1][1] * wt1 + cms[2][1] * wt2 + cms[3][1] * wt3;
  float4 a0 = *(float4*)&cacc[0][4 * t];
  float4 a1 = *(float4*)&cacc[1][4 * t];
  float4 a2 = *(float4*)&cacc[2][4 * t];
  float4 a3 = *(float4*)&cacc[3][4 * t];
  float4 r;
  r.x = wt0 * a0.x + wt1 * a1.x + wt2 * a2.x + wt3 * a3.x;
  r.y = wt0 * a0.y + wt1 * a1.y + wt2 * a2.y + wt3 * a3.y;
  r.z = wt0 * a0.z + wt1 * a1.z + wt2 * a2.z + wt3 * a3.z;
  r.w = wt0 * a0.w + wt1 * a1.w + wt2 * a2.w + wt3 * a3.w;
  *(float4*)(c0part + ((size_t)sc * 32 + b) * 1024 + 4 * t) = r;
  if (t == 0) {
    msum_part[((size_t)sc * 32 + b) * 2 + 0] = mb;
    msum_part[((size_t)sc * 32 + b) * 2 + 1] = sb;
  }
}

// ---------------------------------------------------------------------------
// K6: grid 160. Blocks 0..127: c0 combine. Blocks 128..159: top-4 per row.
// ---------------------------------------------------------------------------
__device__ __forceinline__ bool vi_better(float av, int ai, float bv, int bi) {
  return av > bv || (av == bv && ai < bi);
}

__global__ __launch_bounds__(256) void attn_finish(
    const float* __restrict__ c0part, const float* __restrict__ msum_part,
    const float* __restrict__ logits, float* __restrict__ c0,
    float* __restrict__ scores, int* __restrict__ sent) {
  int bid = blockIdx.x, t = threadIdx.x;
  int b = (bid < 128) ? (bid >> 2) : (bid - 128);
  float m = -FLT_MAX;
  float ms[CH];
#pragma unroll
  for (int c = 0; c < CH; c++) {
    ms[c] = msum_part[((size_t)c * 32 + b) * 2 + 0];
    m = fmaxf(m, ms[c]);
  }
  float sum = 0.f;
  float wc[CH];
#pragma unroll
  for (int c = 0; c < CH; c++) {
    wc[c] = expf(ms[c] - m);
    sum += msum_part[((size_t)c * 32 + b) * 2 + 1] * wc[c];
  }
  float inv = 1.f / sum;

  if (bid < 128) {
    int h = (bid & 3) * 256 + t;
    float a = 0.f;
#pragma unroll
    for (int c = 0; c < CH; c++)
      a += wc[c] * c0part[((size_t)c * 32 + b) * 1024 + h];
    c0[(size_t)b * HH + h] = a * inv;
    return;
  }

  float tv0 = -FLT_MAX, tv1 = -FLT_MAX, tv2 = -FLT_MAX, tv3 = -FLT_MAX;
  int ti0 = INT_MAX, ti1 = INT_MAX, ti2 = INT_MAX, ti3 = INT_MAX;
#pragma unroll
  for (int it = 0; it < 8; it++) {
    int idx = it * 256 + t;
    float v = logits[(size_t)b * SS + idx];
    if (vi_better(v, idx, tv3, ti3)) {
      tv3 = v; ti3 = idx;
      if (vi_better(tv3, ti3, tv2, ti2)) { float fv = tv2; int fi = ti2; tv2 = tv3; ti2 = ti3; tv3 = fv; ti3 = fi; }
      if (vi_better(tv2, ti2, tv1, ti1)) { float fv = tv1; int fi = ti1; tv1 = tv2; ti1 = ti2; tv2 = fv; ti2 = fi; }
      if (vi_better(tv1, ti1, tv0, ti0)) { float fv = tv0; int fi = ti0; tv0 = tv1; ti0 = ti1; tv1 = fv; ti1 = fi; }
    }
  }
  __shared__ float sv[256][4];
  __shared__ int si[256][4];
  sv[t][0] = tv0; sv[t][1] = tv1; sv[t][2] = tv2; sv[t][3] = tv3;
  si[t][0] = ti0; si[t][1] = ti1; si[t][2] = ti2; si[t][3] = ti3;
  __syncthreads();
  for (int off = 128; off; off >>= 1) {
    if (t < off) {
      float bv0 = sv[t + off][0], bv1 = sv[t + off][1], bv2 = sv[t + off][2], bv3 = sv[t + off][3];
      int bi0 = si[t + off][0], bi1 = si[t + off][1], bi2 = si[t + off][2], bi3 = si[t + off][3];
      float mv0, mv1, mv2, mv3; int mi0, mi1, mi2, mi3;
      if (vi_better(tv0, ti0, bv3, bi3)) { mv0 = tv0; mi0 = ti0; } else { mv0 = bv3; mi0 = bi3; }
      if (vi_better(tv1, ti1, bv2, bi2)) { mv1 = tv1; mi1 = ti1; } else { mv1 = bv2; mi1 = bi2; }
      if (vi_better(tv2, ti2, bv1, bi1)) { mv2 = tv2; mi2 = ti2; } else { mv2 = bv1; mi2 = bi1; }
      if (vi_better(tv3, ti3, bv0, bi0)) { mv3 = tv3; mi3 = ti3; } else { mv3 = bv0; mi3 = bi0; }
      if (!vi_better(mv0, mi0, mv2, mi2)) { float fv = mv0; int fi = mi0; mv0 = mv2; mi0 = mi2; mv2 = fv; mi2 = fi; }
      if (!vi_better(mv1, mi1, mv3, mi3)) { float fv = mv1; int fi = mi1; mv1 = mv3; mi1 = mi3; mv3 = fv; mi3 = fi; }
      if (!vi_better(mv0, mi0, mv1, mi1)) { float fv = mv0; int fi = mi0; mv0 = mv1; mi0 = mi1; mv1 = fv; mi1 = fi; }
      if (!vi_better(mv2, mi2, mv3, mi3)) { float fv = mv2; int fi = mi2; mv2 = mv3; mi2 = mi3; mv3 = fv; mi3 = fi; }
      tv0 = mv0; tv1 = mv1; tv2 = mv2; tv3 = mv3;
      ti0 = mi0; ti1 = mi1; ti2 = mi2; ti3 = mi3;
      sv[t][0] = tv0; sv[t][1] = tv1; sv[t][2] = tv2; sv[t][3] = tv3;
      si[t][0] = ti0; si[t][1] = ti1; si[t][2] = ti2; si[t][3] = ti3;
    }
    __syncthreads();
  }
  if (t == 0) {
    scores[b * KK + 0] = expf(tv0 - m) * inv; sent[b * KK + 0] = ti0;
    scores[b * KK + 1] = expf(tv1 - m) * inv; sent[b * KK + 1] = ti1;
    scores[b * KK + 2] = expf(tv2 - m) * inv; sent[b * KK + 2] = ti2;
    scores[b * KK + 3] = expf(tv3 - m) * inv; sent[b * KK + 3] = ti3;
  }
}

// ---------------------------------------------------------------------------
// K7: selection + ctx (shuffle-free) + gathers. grid (4,32), block 256.
// ---------------------------------------------------------------------------
__global__ __launch_bounds__(256) void ctx_sel_gather(
    const float* __restrict__ scores, const int* __restrict__ sent,
    const float* __restrict__ evidence, const int* __restrict__ esi,
    const float* __restrict__ Wv, const float* __restrict__ bvec,
    const float* __restrict__ c0, const float* __restrict__ hnew,
    const float* __restrict__ attn_in, const float* __restrict__ logits,
    const float* __restrict__ mask, float* __restrict__ out0,
    float* __restrict__ out1, float* __restrict__ out2,
    float* __restrict__ out3, float* __restrict__ out4,
    float* __restrict__ out5) {
  __shared__ int s_sh;
  __shared__ float cs[HH];
  int jq = blockIdx.x, b = blockIdx.y, t = threadIdx.x;
  if (t == 0) {
    int r = b >> 2, j = b & 3;
    float ls[16];
    bool used[16];
    for (int k1 = 0; k1 < 4; k1++)
      for (int k2 = 0; k2 < 4; k2++)
        ls[k1 * 4 + k2] = -logf(scores[(r * 4 + k1) * 4 + k2]) + evidence[r * 4 + k1];
    for (int i = 0; i < 16; i++) used[i] = false;
    int best = 0;
    float bvv = FLT_MAX;
    for (int jj = 0; jj <= j; jj++) {
      best = 0;
      bvv = FLT_MAX;
      for (int i = 0; i < 16; i++)
        if (!used[i] && ls[i] < bvv) { bvv = ls[i]; best = i; }
      used[best] = true;
    }
    int k1 = best >> 2, k2 = best & 3;
    int sSel = r * 4 + k1;
    s_sh = sSel;
    if (jq == 0) {
      out5[b] = bvv;
      out2[b * 3 + 0] = (float)esi[sSel * 2 + 0];
      out2[b * 3 + 1] = (float)esi[sSel * 2 + 1];
      out2[b * 3 + 2] = (float)sent[sSel * 4 + k2];
    }
  }
  __syncthreads();
  int s = s_sh;
  *(float4*)&cs[4 * t] = *(const float4*)(c0 + (size_t)s * HH + 4 * t);
  __syncthreads();
  {
    int j = jq * 256 + t;
    const float4* w4 = (const float4*)(Wv + (size_t)j * HH);
    float acc = bvec[j];
#pragma unroll 8
    for (int k4 = 0; k4 < 256; k4++) {
      float4 wv = w4[k4];
      float4 cc = *(const float4*)&cs[4 * k4];
      acc += wv.x * cc.x + wv.y * cc.y + wv.z * cc.z + wv.w * cc.w;
    }
    out0[(size_t)b * HH + j] = acc;
  }
  out1[(size_t)b * HH + jq * 256 + t] = hnew[(size_t)s * HH + jq * 256 + t];
#pragma unroll
  for (int p = 0; p < 2; p++) {
    *(float2*)(out3 + ((size_t)p * BB + b) * SS + jq * 512 + 2 * t) =
        *(const float2*)(attn_in + ((size_t)p * BB + s) * SS + jq * 512 + 2 * t);
  }
  *(float2*)(out3 + ((size_t)2 * BB + b) * SS + jq * 512 + 2 * t) =
      *(const float2*)(logits + (size_t)s * SS + jq * 512 + 2 * t);
  *(float2*)(out4 + (size_t)b * SS + jq * 512 + 2 * t) =
      *(const float2*)(mask + (size_t)s * SS + jq * 512 + 2 * t);
}

extern "C" void kernel_launch(void* const* d_in, const int* in_sizes, int n_in,
                              void* d_out, int out_size, void* d_ws, size_t ws_size,
                              hipStream_t stream) {
  const float* h_old = (const float*)d_in[0];
  const float* x     = (const float*)d_in[1];
  const float* eo    = (const float*)d_in[2];
  const float* attn_in = (const float*)d_in[3];
  const float* mask  = (const float*)d_in[4];
  const float* evidence = (const float*)d_in[5];
  const int*   esi   = (const int*)d_in[6];
  const float* W_ih  = (const float*)d_in[7];
  const float* W_hh  = (const float*)d_in[8];
  const float* b_ih  = (const float*)d_in[9];
  const float* b_hh  = (const float*)d_in[10];
  const float* Wk    = (const float*)d_in[11];
  const float* bk    = (const float*)d_in[12];
  const float* Wv    = (const float*)d_in[13];
  const float* bv    = (const float*)d_in[14];

  float* w = (float*)d_ws;
  float* h_new  = w + 0;          // 32768
  float* q      = w + 32768;      // 32768
  float* logits = w + 65536;      // 65536
  float* scores = w + 131072;     // 128
  int*   sent   = (int*)(w + 131200);  // 128
  float* c0     = w + 131328;     // 32768
  float* msum_part = w + 164096;  // 2048
  float* c0part = w + 166144;     // 1,048,576
  float* gpart  = w + 1214720;    // 3,145,728
  float* qpart  = w + 4360448;    // 1,048,576

  float* out0 = (float*)d_out;   // result (32,1,1024)
  float* out1 = out0 + 32768;    // hidden (1,32,1024)
  float* out2 = out1 + 32768;    // new_evidence_sentence_index (32,3)
  float* out3 = out2 + 96;       // new_attention_scores (3,32,1,2048)
  float* out4 = out3 + 196608;   // new_attention_mask (32,1,2048)
  float* out5 = out4 + 65536;    // new_evidence_scores (32,)

  gates_partial<<<dim3(24, 16, 4), 256, 0, stream>>>(x, h_old, W_ih, W_hh, gpart);
  gru_pw<<<dim3(32, 4), 256, 0, stream>>>(gpart, b_ih, b_hh, h_old, h_new);
  q_partial<<<dim3(4, 32, 4), 256, 0, stream>>>(h_new, Wk, qpart);
  q_reduce<<<128, 256, 0, stream>>>(qpart, q);
  fused_attn<<<dim3(CH, BB), 256, 0, stream>>>(eo, q, h_new, bk, mask, logits,
                                               c0part, msum_part);
  attn_finish<<<160, 256, 0, stream>>>(c0part, msum_part, logits, c0, scores, sent);
  ctx_sel_gather<<<dim3(4, BB), 256, 0, stream>>>(
      scores, sent, evidence, esi, Wv, bv, c0, h_new, attn_in, logits, mask,
      out0, out1, out2, out3, out4, out5);
}